// Round 6
// baseline (443.262 us; speedup 1.0000x reference)
//
#include <hip/hip_runtime.h>
#include <math.h>

// Problem dims (fixed)
#define BB   16
#define SS   2048
#define DIN  256
#define DEMB 512
#define DKQ  512
#define DVV  512

typedef _Float16 f16;
typedef _Float16 half8  __attribute__((ext_vector_type(8)));
typedef _Float16 f16x4  __attribute__((ext_vector_type(4)));
typedef float    f32x4  __attribute__((ext_vector_type(4)));
typedef float    f32x16 __attribute__((ext_vector_type(16)));

#define GLOAD_LDS16(gp, lp)                                                        \
  __builtin_amdgcn_global_load_lds(                                                \
      (const __attribute__((address_space(1))) unsigned int*)(gp),                 \
      (__attribute__((address_space(3))) unsigned int*)(lp), 16, 0, 0)

// V slot permute: decorrelates LDS bank-start across dv rows (2-way max)
__device__ __forceinline__ int vperm(int dv) { return (dv ^ (dv >> 2)) & 3; }

// ---------------------------------------------------------------------------
// Kernel 0: split x (fp32) -> Xh, Xl (fp16 pair, exact to ~2^-22)
// ---------------------------------------------------------------------------
__global__ __launch_bounds__(256) void prep_x(
    const float* __restrict__ x, f16* __restrict__ Xh, f16* __restrict__ Xl)
{
    int idx = blockIdx.x * 256 + threadIdx.x;
    float4 v = ((const float4*)x)[idx];
    f16x4 h, l;
    h.x = (f16)v.x; l.x = (f16)(v.x - (float)h.x);
    h.y = (f16)v.y; l.y = (f16)(v.y - (float)h.y);
    h.z = (f16)v.z; l.z = (f16)(v.z - (float)h.z);
    h.w = (f16)v.w; l.w = (f16)(v.w - (float)h.w);
    ((f16x4*)Xh)[idx] = h;
    ((f16x4*)Xl)[idx] = l;
}

// ---------------------------------------------------------------------------
// Kernel 1: fuse weights W' = W_embed @ W (fp32 math), output TRANSPOSED
// Wth [z][n=512][k=256], f16 high part. Tiled: block = 256 n-cols x 8 m-rows.
// ---------------------------------------------------------------------------
__global__ __launch_bounds__(256) void fuse_weights(
    const float* __restrict__ We, const float* __restrict__ Wk,
    const float* __restrict__ Wq, const float* __restrict__ Wv,
    f16* __restrict__ Wth)
{
    const int n  = blockIdx.x * 256 + threadIdx.x;   // 0..511
    const int m0 = blockIdx.y * 8;                   // 8 m-rows per block
    const int z  = blockIdx.z;
    const float* Wsrc = (z == 0) ? Wk : (z == 1) ? Wq : Wv;

    float acc[8];
#pragma unroll
    for (int j = 0; j < 8; ++j) acc[j] = 0.f;

#pragma unroll 8
    for (int kk = 0; kk < DEMB; ++kk) {
        float wv = Wsrc[kk * 512 + n];
#pragma unroll
        for (int j = 0; j < 8; ++j)
            acc[j] += We[(m0 + j) * DEMB + kk] * wv;
    }
#pragma unroll
    for (int j = 0; j < 8; ++j)
        Wth[(size_t)z * 131072 + n * 256 + m0 + j] = (f16)acc[j];
}

// ---------------------------------------------------------------------------
// Kernel 2 (v3): MFMA projections, 2-term fp16 split (Ah*Bh + Al*Bh).
// 768 blocks x 256 threads (4 waves), ALL co-resident: 3 blocks/CU
// (48 KB LDS each), cross-block slip hides every barrier stall.
// Block = 128 m-rows x ALL 512 n (nb-loop inside) x one z:
//   A re-read across blocks drops 12x -> 3x (96 MB, hidden under DS work);
//   within-block A re-reads are the block's own L2-hot panel.
// K-chunk 32, double-buffered (2 x 24 KB), ONE barrier per chunk
// (stage c+1 at interval top, vmcnt(0) only at the barrier).
// 64B rows ([row][32k]) are bank-conflict-free without swizzle.
// XCD ownership: xcd = gid&7 owns batches {xcd, xcd+8} == attn2's decode,
// so attention starts with L2-warm K/Q/V.
//   z=0 -> Kh [row][512]; z=1 -> Qh [row][512] PRE-SCALED by log2(e);
//   z=2 -> Vt2 [b][tile(64)][dv(512)][32 keys], slots permuted by vperm(dv)
// ---------------------------------------------------------------------------
#define CAH 0        // A-high: 128 rows x 32 k = 4096 shorts (8 KB)
#define CAL 4096     // A-low
#define CBH 8192     // B: 128 n-rows x 32 k = 4096 shorts
#define CBUF 12288   // one buffer = 12288 shorts (24 KB); x2 = 48 KB

__global__ __launch_bounds__(256, 3) void qkv_gemm(
    const f16* __restrict__ Xh, const f16* __restrict__ Xl,
    const f16* __restrict__ Wth,
    f16* __restrict__ Kh, f16* __restrict__ Qh, f16* __restrict__ Vt2)
{
    __shared__ __align__(16) short smq[24576];   // 48 KB

    const int tid  = threadIdx.x;
    const int lane = tid & 63;
    const int w    = tid >> 6;                   // 0..3
    const int l15  = lane & 15;
    const int quad = lane >> 4;

    // XCD-ownership decode: xcd owns batches {xcd, xcd+8} (matches attn2).
    const int gid = blockIdx.x;                  // 0..767
    const int xcd = gid & 7;
    const int j   = gid >> 3;                    // 0..95
    const int z   = j % 3;
    const int ml  = j / 3;                       // 0..31 (16 panels/batch)
    const int p   = (ml < 16) ? (xcd * 16 + ml) : ((xcd + 8) * 16 + (ml - 16));
    const int m0  = p * 128;
    const int bb  = p >> 4;                      // batch

    const int wm = (w >> 1) * 64, wn = (w & 1) * 64;

    const f16* Bh = Wth + (size_t)z * 131072;

    const int srow  = lane >> 2;                 // staging: row-within-16
    const int sslot = (lane & 3) * 8;            // staging: 16B k-slot

    // Stage chunk c of (A rows m0.., B rows n0..) into buffer `buf` (24 KB).
    // Per wave: 16-row groups; per thread 6 gload_lds.
    auto stage = [&](int n0, int c, int buf) {
        const int k0 = c * 32;
#pragma unroll
        for (int i = 0; i < 2; ++i) {
            int rb = w * 32 + i * 16;
            GLOAD_LDS16(Xh + (size_t)(m0 + rb + srow) * 256 + k0 + sslot,
                        smq + buf + CAH + rb * 32);
            GLOAD_LDS16(Xl + (size_t)(m0 + rb + srow) * 256 + k0 + sslot,
                        smq + buf + CAL + rb * 32);
            GLOAD_LDS16(Bh + (size_t)(n0 + rb + srow) * 256 + k0 + sslot,
                        smq + buf + CBH + rb * 32);
        }
    };

    for (int nb = 0; nb < 4; ++nb) {
        const int n0 = nb * 128;

        // ---- prologue: stage chunk 0 into buf0 ----
        stage(n0, 0, 0);
        asm volatile("s_waitcnt vmcnt(0)" ::: "memory");
        __builtin_amdgcn_s_barrier();
        __builtin_amdgcn_sched_barrier(0);

        f32x4 acc[4][4];
#pragma unroll
        for (int i = 0; i < 4; ++i)
#pragma unroll
            for (int jj = 0; jj < 4; ++jj) acc[i][jj] = (f32x4){0.f, 0.f, 0.f, 0.f};

        for (int c = 0; c < 8; ++c) {
            const int bufc = (c & 1) * CBUF;
            const int bufn = ((c + 1) & 1) * CBUF;

            if (c < 7) stage(n0, c + 1, bufn);   // consumed NEXT interval

            __builtin_amdgcn_s_setprio(1);
            half8 ah[4], al[4], bh[4];
#pragma unroll
            for (int i = 0; i < 4; ++i) {
                ah[i] = *(const half8*)(smq + bufc + CAH + (wm + i * 16 + l15) * 32 + quad * 8);
                al[i] = *(const half8*)(smq + bufc + CAL + (wm + i * 16 + l15) * 32 + quad * 8);
                bh[i] = *(const half8*)(smq + bufc + CBH + (wn + i * 16 + l15) * 32 + quad * 8);
            }
#pragma unroll
            for (int mi = 0; mi < 4; ++mi)
#pragma unroll
                for (int ni = 0; ni < 4; ++ni) {
                    acc[mi][ni] = __builtin_amdgcn_mfma_f32_16x16x32_f16(ah[mi], bh[ni], acc[mi][ni], 0, 0, 0);
                    acc[mi][ni] = __builtin_amdgcn_mfma_f32_16x16x32_f16(al[mi], bh[ni], acc[mi][ni], 0, 0, 0);
                }
            __builtin_amdgcn_s_setprio(0);

            asm volatile("s_waitcnt vmcnt(0) lgkmcnt(0)" ::: "memory");
            __builtin_amdgcn_s_barrier();
            __builtin_amdgcn_sched_barrier(0);
        }

        // ---- epilogue for this nb (both buffers free; 48 KB usable) ----
        if (z < 2) {
            const float qsc = (z == 1) ? 1.44269504f : 1.0f;
#pragma unroll
            for (int mi = 0; mi < 4; ++mi)
#pragma unroll
                for (int ni = 0; ni < 4; ++ni)
#pragma unroll
                    for (int r = 0; r < 4; ++r)
                        *(f16*)(smq + (wm + mi * 16 + quad * 4 + r) * 136 + wn + ni * 16 + l15) =
                            (f16)(acc[mi][ni][r] * qsc);
            __syncthreads();
            f16* Out = (z == 0) ? Kh : Qh;
            int cg = tid & 15;
            int rt = tid >> 4;                   // 0..15
#pragma unroll
            for (int jj = 0; jj < 8; ++jj) {
                int row = jj * 16 + rt;
                half8 v = *(const half8*)(smq + row * 136 + cg * 8);
                *(half8*)&Out[(size_t)(m0 + row) * 512 + n0 + cg * 8] = v;
            }
        } else {
            // transpose in LDS: [dv_local 128][key_local 128], stride 136
#pragma unroll
            for (int mi = 0; mi < 4; ++mi)
#pragma unroll
                for (int ni = 0; ni < 4; ++ni)
#pragma unroll
                    for (int r = 0; r < 4; ++r)
                        *(f16*)(smq + (wn + ni * 16 + l15) * 136 + wm + mi * 16 + quad * 4 + r) =
                            (f16)acc[mi][ni][r];
            __syncthreads();
            int kb0 = m0 & 2047;
            int cg = tid & 15;                   // key 16B-group 0..15 (128 keys)
            int rt = tid >> 4;                   // 0..15
#pragma unroll
            for (int jj = 0; jj < 8; ++jj) {
                int dvr = jj * 16 + rt;          // 0..127
                int dv  = n0 + dvr;
                half8 v = *(const half8*)(smq + dvr * 136 + cg * 8);
                int t  = (kb0 >> 5) + (cg >> 2); // key tile
                int s  = (cg & 3) ^ vperm(dv);   // permuted 16B slot
                *(half8*)&Vt2[(((size_t)bb * 64 + t) * 512 + dv) * 32 + s * 8] = v;
            }
        }
        __syncthreads();   // LDS free before next nb's prologue staging
    }
}

// ---------------------------------------------------------------------------
// Kernel 3: MFMA flash attention — ONE barrier per tile (R3, verified 222us),
// SWAPPED-OPERAND scores + lane-local softmax. UNCHANGED.
// ---------------------------------------------------------------------------
#define LKA 0        // K buf0: 32 keys x 512 d   = 16384 shorts
#define LKB 16384    // K buf1
#define LVA 32768    // V buf0: 512 dv x 32 keys  = 16384 shorts
#define LVB 49152    // V buf1
#define LPA 65536    // P buf0: 128 q x stride 40 =  5120 shorts
#define LPB 70656    // P buf1
#define LAA 75776    // alpha buf0/buf1: 2 x 128 floats = 512 shorts
#define LLL 76288    // l[128] floats             =   256 shorts
#define LFA 76544    // flags buf0/buf1: 2 x 8 ints = 32 shorts
#define LTOT 76576   // 153152 bytes (< 160 KiB)

#define THR_L2 11.5416f   // defer-max threshold: 8 nats in log2 units

__global__ __launch_bounds__(512, 2) void attn2(
    const f16* __restrict__ Qh, const f16* __restrict__ Kh,
    const f16* __restrict__ Vt2, float* __restrict__ Y)
{
    __shared__ __align__(16) short sm[LTOT];

    const int tid  = threadIdx.x;
    const int lane = tid & 63;
    const int w    = tid >> 6;                    // 0..7
    // XCD-aware decode: xcd = gid&7; b = (gid&7) + 8*(gid>>7); q0 = ((gid>>3)&15)*128
    const int gid  = blockIdx.x;
    const int b    = (gid & 7) + ((gid >> 7) << 3);
    const int q0   = ((gid >> 3) & 15) << 7;
    const int l15  = lane & 15;
    const int quad = lane >> 4;
    const int l31  = lane & 31;
    const int lhi  = lane >> 5;
    const int qquad = w >> 1, dvhalf = w & 1;     // PV mapping: 4 q-quads x 2 dv-halves

    const f16* Khb  = Kh  + (size_t)b * SS * 512;
    const f16* Vt2b = Vt2 + (size_t)b * 64 * 512 * 32;

    // ---- Q fragments (resident): wave w, q rows q0+16w .. +15 ----
    half8 qh[16];
    {
        const half8* qhp = (const half8*)(Qh + ((size_t)(b * SS + q0 + w * 16 + l15)) * 512);
#pragma unroll
        for (int ks = 0; ks < 16; ++ks) qh[ks] = qhp[ks * 4 + quad];
    }

    f32x16 O[8];
#pragma unroll
    for (int n = 0; n < 8; ++n)
#pragma unroll
        for (int r = 0; r < 16; ++r) O[n][r] = 0.f;

    float m_pr = -1e30f;   // running max, log2 domain (per lane's q row)
    float l_r  = 0.f;      // running denom (per lane's q row)

    // 8 waves x 4 instrs = 32 KB per tile for each of K and V
    auto stage_K = [&](int t, int lk) {
        const int kb = t * 32;
#pragma unroll
        for (int i = 0; i < 4; ++i) {
            int key = w * 4 + i;
            const f16* g = Khb + ((size_t)(kb + key)) * 512 + ((lane ^ (key & 15)) << 3);
            GLOAD_LDS16(g, sm + lk + key * 512);
        }
    };
    auto stage_V = [&](int t, int lv) {
        const f16* gbase = Vt2b + (size_t)t * 16384 + lane * 8;
#pragma unroll
        for (int i = 0; i < 4; ++i) {
            int off = (w * 4 + i) * 512;
            GLOAD_LDS16(gbase + off, sm + lv + off);
        }
    };

    // ---- PV(tp): rescale O by alpha(tp) then O += P(tp) * V(tp) ----
    auto do_pv = [&](int LPp, int LVp, const float* ap, const int* fp) {
        if (fp[2 * qquad] | fp[2 * qquad + 1]) {
            float av[16];
#pragma unroll
            for (int r = 0; r < 16; ++r) {
                int row = (r & 3) + ((r >> 2) << 3) + (lhi << 2);
                av[r] = ap[qquad * 32 + row];
            }
#pragma unroll
            for (int n = 0; n < 8; ++n)
#pragma unroll
                for (int r = 0; r < 16; ++r) O[n][r] *= av[r];
        }
        half8 pA[2];
#pragma unroll
        for (int ks = 0; ks < 2; ++ks) {
            int q  = qquad * 32 + l31;
            int uk = ks * 2 + lhi;
            pA[ks] = *(const half8*)(sm + LPp + q * 40 + uk * 8);
        }
#pragma unroll
        for (int ks = 0; ks < 2; ++ks) {
#pragma unroll
            for (int n = 0; n < 8; ++n) {
                int dv = dvhalf * 256 + n * 32 + l31;
                int uk = ks * 2 + lhi;
                half8 bf = *(const half8*)(sm + LVp + dv * 32 + ((uk ^ vperm(dv)) << 3));
                O[n] = __builtin_amdgcn_mfma_f32_32x32x16_f16(pA[ks], bf, O[n], 0, 0, 0);
            }
        }
    };

    // ---- prologue: stage K(0) into buf0, sync ----
    stage_K(0, LKA);
    asm volatile("s_waitcnt vmcnt(0)" ::: "memory");
    __builtin_amdgcn_s_barrier();
    __builtin_amdgcn_sched_barrier(0);

    for (int t = 0; t < 64; ++t) {
        const int cur = t & 1;
        const int prv = cur ^ 1;
        const int LKc = LKA + cur * 16384;   // K(t)
        const int LKn = LKA + prv * 16384;   // K(t+1) dest
        const int LVc = LVA + cur * 16384;   // V(t) dest
        const int LVp = LVA + prv * 16384;   // V(t-1)
        const int LPc = LPA + cur * 5120;    // P(t) dest
        const int LPp = LPA + prv * 5120;    // P(t-1)
        float* aw = (float*)(sm + LAA + cur * 256);
        const float* ap = (const float*)(sm + LAA + prv * 256);
        int* fw = (int*)(sm + LFA + cur * 16);
        const int* fp = (const int*)(sm + LFA + prv * 16);

        // prefetch: K(t+1) and V(t); both consumed NEXT interval
        if (t + 1 < 64) stage_K(t + 1, LKn);
        stage_V(t, LVc);

        __builtin_amdgcn_s_setprio(1);
        // ---- PV(t-1) ----
        if (t > 0) do_pv(LPp, LVp, ap, fp);

        // ---- scores(t), SWAPPED: S^T = K * Q^T (16x16x32) ----
        f32x4 S[2];
        S[0] = (f32x4){0.f, 0.f, 0.f, 0.f};
        S[1] = (f32x4){0.f, 0.f, 0.f, 0.f};
#pragma unroll
        for (int ks = 0; ks < 16; ++ks) {
#pragma unroll
            for (int n = 0; n < 2; ++n) {
                int key = n * 16 + l15;
                int ud  = ks * 4 + quad;
                half8 bf = *(const half8*)(sm + LKc + key * 512 + ((ud ^ l15) << 3));
                S[n] = __builtin_amdgcn_mfma_f32_16x16x32_f16(bf, qh[ks], S[n], 0, 0, 0);
            }
        }
        __builtin_amdgcn_s_setprio(0);

        // ---- lane-local online softmax (log2 domain), defer-max ----
        float mx = fmaxf(fmaxf(fmaxf(S[0][0], S[0][1]), fmaxf(S[0][2], S[0][3])),
                         fmaxf(fmaxf(S[1][0], S[1][1]), fmaxf(S[1][2], S[1][3])));
        mx = fmaxf(mx, __shfl_xor(mx, 16, 64));
        mx = fmaxf(mx, __shfl_xor(mx, 32, 64));
        bool up  = mx > m_pr + THR_L2;          // defer small max growth
        float mn = up ? mx : m_pr;
        float al = up ? __builtin_amdgcn_exp2f(m_pr - mn) : 1.0f;
        m_pr = mn;

        float p0 = __builtin_amdgcn_exp2f(S[0][0] - mn);
        float p1 = __builtin_amdgcn_exp2f(S[0][1] - mn);
        float p2 = __builtin_amdgcn_exp2f(S[0][2] - mn);
        float p3 = __builtin_amdgcn_exp2f(S[0][3] - mn);
        float p4 = __builtin_amdgcn_exp2f(S[1][0] - mn);
        float p5 = __builtin_amdgcn_exp2f(S[1][1] - mn);
        float p6 = __builtin_amdgcn_exp2f(S[1][2] - mn);
        float p7 = __builtin_amdgcn_exp2f(S[1][3] - mn);
        float sum = ((p0 + p1) + (p2 + p3)) + ((p4 + p5) + (p6 + p7));
        sum += __shfl_xor(sum, 16, 64);
        sum += __shfl_xor(sum, 32, 64);
        l_r = l_r * al + sum;

        {
            int q = w * 16 + l15;
            f16x4 lo, hi;
            lo.x = (f16)p0; lo.y = (f16)p1; lo.z = (f16)p2; lo.w = (f16)p3;
            hi.x = (f16)p4; hi.y = (f16)p5; hi.z = (f16)p6; hi.w = (f16)p7;
            *(f16x4*)(sm + LPc + q * 40 + quad * 4)      = lo;  // keys quad*4..+3
            *(f16x4*)(sm + LPc + q * 40 + 16 + quad * 4) = hi;  // keys 16+quad*4..+3
        }

        unsigned long long bm = __ballot(up);
        if (lane == 0) fw[w] = (bm != 0ULL) ? 1 : 0;
        if (quad == 0) aw[w * 16 + l15] = al;

        // ---- single barrier: P/alpha/flags(t) visible; K(t+1)/V(t) landed ----
        asm volatile("s_waitcnt vmcnt(0) lgkmcnt(0)" ::: "memory");
        __builtin_amdgcn_s_barrier();
        __builtin_amdgcn_sched_barrier(0);
    }

    // ---- final PV(63) (buffers at parity of t=63 -> cur=1) ----
    do_pv(LPA + 5120, LVA + 16384,
          (const float*)(sm + LAA + 256), (const int*)(sm + LFA + 16));

    // ---- epilogue: O /= l, store ----
    float* lptr = (float*)(sm + LLL);
    if (quad == 0) lptr[w * 16 + l15] = l_r;
    __syncthreads();
    float linv[16];
#pragma unroll
    for (int r = 0; r < 16; ++r) {
        int row = (r & 3) + ((r >> 2) << 3) + (lhi << 2);
        linv[r] = 1.0f / lptr[qquad * 32 + row];
    }
#pragma unroll
    for (int n = 0; n < 8; ++n) {
#pragma unroll
        for (int r = 0; r < 16; ++r) {
            int row = (r & 3) + ((r >> 2) << 3) + (lhi << 2);
            Y[((size_t)(b * SS + q0 + qquad * 32 + row)) * 512 + dvhalf * 256 + n * 32 + l31] =
                O[n][r] * linv[r];
        }
    }
}

// ---------------------------------------------------------------------------
// Host launcher
// ---------------------------------------------------------------------------
extern "C" void kernel_launch(void* const* d_in, const int* in_sizes, int n_in,
                              void* d_out, int out_size, void* d_ws, size_t ws_size,
                              hipStream_t stream)
{
    const float* x  = (const float*)d_in[0];
    const float* We = (const float*)d_in[1];
    const float* Wk = (const float*)d_in[2];
    const float* Wq = (const float*)d_in[3];
    const float* Wv = (const float*)d_in[4];
    float* out = (float*)d_out;

    const size_t WSZ = 3 * 256 * 512;          // 393216
    const size_t XSZ = (size_t)BB * SS * DIN;  // 8388608
    const size_t MSZ = (size_t)BB * SS * 512;  // 16777216

    f16* Wth = (f16*)d_ws;
    f16* Wtl = Wth + WSZ;                      // (unused slot kept for layout)
    f16* Xh  = Wtl + WSZ;
    f16* Xl  = Xh + XSZ;
    f16* Qh  = Xl + XSZ;
    f16* Kh  = Qh + MSZ;
    f16* Vt2 = Kh + MSZ;

    prep_x<<<dim3(XSZ / 4 / 256), dim3(256), 0, stream>>>(x, Xh, Xl);

    fuse_weights<<<dim3(2, 32, 3), dim3(256), 0, stream>>>(We, Wk, Wq, Wv, Wth);

    qkv_gemm<<<dim3(768), dim3(256), 0, stream>>>(
        Xh, Xl, Wth, Kh, Qh, Vt2);

    attn2<<<dim3(256), dim3(512), 0, stream>>>(Qh, Kh, Vt2, out);
}